// Round 5
// baseline (156.405 us; speedup 1.0000x reference)
//
#include <hip/hip_runtime.h>

#define N 8192
#define T 512
#define S 4

__device__ __forceinline__ float dot4(float4 a, float4 b) {
    return a.x*b.x + a.y*b.y + a.z*b.z + a.w*b.w;
}

// One block (256 thr, 4 waves) per n. Bias phase: fully-coalesced register
// loads + shfl_xor dot-reduction (no big LDS staging). Scan phase: wave w
// scans sample s=w with the chunk-interleaved weighted prefix scan.
__global__ __launch_bounds__(256, 6) void k_fused(
        const float* __restrict__ drivers,
        const float* __restrict__ cov,
        const float* __restrict__ Y,
        const float* __restrict__ eps,
        const float* __restrict__ tilde_psi,
        const float* __restrict__ gamma_w,
        const float* __restrict__ alpha_w,
        const float* __restrict__ alpha_Y_lag,
        const float* __restrict__ log_tilde_sigma,
        const float* __restrict__ mu_init,
        const float* __restrict__ log_sigma_init,
        float* __restrict__ Zout,
        float* __restrict__ muout,
        float* __restrict__ lvout) {
    __shared__ __align__(16) float b_s[T];           // 2 KB only

    const int tid  = threadIdx.x;
    const int lane = tid & 63;
    const int w    = tid >> 6;        // wave id == sample s
    const int n    = blockIdx.x;

    const float psi    = tilde_psi[0];
    const float lts    = log_tilde_sigma[0];
    const float lsi    = log_sigma_init[0];
    const float sigma  = expf(lts);
    const float sigma0 = expf(lsi);
    const float aY     = alpha_Y_lag[0];
    const float mu0c   = mu_init[0];

    const float4* g4 = (const float4*)gamma_w;
    const float4* a4 = (const float4*)alpha_w;
    const float4 g0 = g4[0], g1 = g4[1];
    const float4 w0 = a4[0], w1 = a4[1], w2 = a4[2], w3 = a4[3];
    // per-thread fixed weight chunk (uniform selects, no runtime indexing)
    const float4 myg = (tid & 1) ? g1 : g0;
    const float4 myw = (tid & 1) ? ((tid & 2) ? w3 : w1)
                                 : ((tid & 2) ? w2 : w0);

    // ---- issue ALL global loads upfront (max MLP, no barriers between) ----
    const float4* drv4 = (const float4*)drivers + (size_t)n * (T * 2); // 1024
    const float4* cov4 = (const float4*)cov     + (size_t)n * (T * 4); // 2048
    const float*  Yrow = Y + (size_t)n * T;

    float4 dL[4], cL[8];
    #pragma unroll
    for (int p = 0; p < 4; ++p) dL[p] = drv4[p * 256 + tid];
    #pragma unroll
    for (int q = 0; q < 8; ++q) cL[q] = cov4[q * 256 + tid];

    const size_t chain = ((size_t)w * N + n) * (T / 4);   // float4 units
    const float4* e4 = (const float4*)eps + chain;
    const float4 eA = e4[lane];
    const float4 eB = e4[64 + lane];

    // ---- drivers: row t=(p*256+tid)>>1, chunk tid&1; pair-reduce ----
    #pragma unroll
    for (int p = 0; p < 4; ++p) {
        float pd = dot4(dL[p], myg);
        pd += __shfl_xor(pd, 1);
        if ((lane & 1) == 0) b_s[(p * 256 + tid) >> 1] = pd;
    }
    __syncthreads();

    // ---- covariates: row t=(q*256+tid)>>2, chunk tid&3; quad-reduce ----
    #pragma unroll
    for (int q = 0; q < 8; ++q) {
        const int t = (q * 256 + tid) >> 2;
        const float yv = (t > 0) ? Yrow[t - 1] : 0.f;   // 16 consec addrs/wave
        float pc = dot4(cL[q], myw);
        pc += __shfl_xor(pc, 1);
        pc += __shfl_xor(pc, 2);
        if ((lane & 3) == 0)
            b_s[t] += pc + ((t == 0) ? mu0c : aY * yv);
    }
    __syncthreads();

    // ---- scan phase: wave w handles sample s = w ----
    const float pj1 = psi, pj2 = psi * psi, pj3 = pj2 * psi, pj4 = pj2 * pj2;
    const float wd0 = pj4, wd1 = wd0 * wd0, wd2 = wd1 * wd1,
                wd3 = wd2 * wd2, wd4 = wd3 * wd3, wd5 = wd4 * wd4;
    // p4l = psi^(4*lane)
    float p4l = 1.f;
    {
        float pw = pj4;
        p4l *= (lane & 1)  ? pw : 1.f; pw *= pw;
        p4l *= (lane & 2)  ? pw : 1.f; pw *= pw;
        p4l *= (lane & 4)  ? pw : 1.f; pw *= pw;
        p4l *= (lane & 8)  ? pw : 1.f; pw *= pw;
        p4l *= (lane & 16) ? pw : 1.f; pw *= pw;
        p4l *= (lane & 32) ? pw : 1.f;
    }

    const float4* b_s4 = (const float4*)b_s;
    float4* z4 = (float4*)Zout  + chain;
    float4* m4 = (float4*)muout + chain;
    float4* l4 = (float4*)lvout + chain;
    const float lvv = 2.f * lts;

    float Zlast = 0.f;
    #pragma unroll
    for (int seg = 0; seg < 2; ++seg) {
        const float4 e  = seg ? eB : eA;
        const float4 bq = b_s4[seg * 64 + lane];   // stride-1: 2-way (free)

        const float sg0 = (seg == 0 && lane == 0) ? sigma0 : sigma;
        // local inclusive scan (from zero state)
        const float z0 = bq.x + sg0 * e.x;
        const float z1 = psi * z0 + (bq.y + sigma * e.y);
        const float z2 = psi * z1 + (bq.z + sigma * e.z);
        const float z3 = psi * z2 + (bq.w + sigma * e.w);

        // wave-level weighted inclusive scan of carries (weight psi^4/step)
        float v = z3, up;
        up = __shfl_up(v, 1);  v += (lane >= 1)  ? wd0 * up : 0.f;
        up = __shfl_up(v, 2);  v += (lane >= 2)  ? wd1 * up : 0.f;
        up = __shfl_up(v, 4);  v += (lane >= 4)  ? wd2 * up : 0.f;
        up = __shfl_up(v, 8);  v += (lane >= 8)  ? wd3 * up : 0.f;
        up = __shfl_up(v, 16); v += (lane >= 16) ? wd4 * up : 0.f;
        up = __shfl_up(v, 32); v += (lane >= 32) ? wd5 * up : 0.f;

        float Zprev = __shfl_up(v, 1);
        Zprev = (lane == 0) ? 0.f : Zprev;
        Zprev += p4l * Zlast;                      // bridge from segment A

        const float Z0 = z0 + pj1 * Zprev;
        const float Z1 = z1 + pj2 * Zprev;
        const float Z2 = z2 + pj3 * Zprev;
        const float Z3 = z3 + pj4 * Zprev;

        const float mu0 = Z0 - sg0   * e.x;
        const float mu1 = Z1 - sigma * e.y;
        const float mu2 = Z2 - sigma * e.z;
        const float mu3 = Z3 - sigma * e.w;

        z4[seg * 64 + lane] = make_float4(Z0, Z1, Z2, Z3);
        m4[seg * 64 + lane] = make_float4(mu0, mu1, mu2, mu3);
        l4[seg * 64 + lane] = (seg == 0 && lane == 0)
                            ? make_float4(2.f * lsi, lvv, lvv, lvv)
                            : make_float4(lvv, lvv, lvv, lvv);

        Zlast = __shfl(Z3, 63);                    // Z_255 broadcast
    }
}

extern "C" void kernel_launch(void* const* d_in, const int* in_sizes, int n_in,
                              void* d_out, int out_size, void* d_ws, size_t ws_size,
                              hipStream_t stream) {
    const float* drivers   = (const float*)d_in[0];
    const float* cov       = (const float*)d_in[1];
    const float* Y         = (const float*)d_in[2];
    const float* eps       = (const float*)d_in[3];
    const float* tilde_psi = (const float*)d_in[4];
    const float* gamma_w   = (const float*)d_in[5];
    const float* alpha_w   = (const float*)d_in[6];
    const float* aY        = (const float*)d_in[7];
    const float* lts       = (const float*)d_in[8];
    const float* mu_init   = (const float*)d_in[9];
    const float* lsi       = (const float*)d_in[10];

    float* out   = (float*)d_out;
    const size_t SNT = (size_t)S * N * T;
    float* Zout  = out;
    float* muout = out + SNT;
    float* lvout = out + 2 * SNT;

    k_fused<<<N, 256, 0, stream>>>(drivers, cov, Y, eps, tilde_psi,
                                   gamma_w, alpha_w, aY, lts, mu_init, lsi,
                                   Zout, muout, lvout);
}